// Round 5
// baseline (569.597 us; speedup 1.0000x reference)
//
#include <hip/hip_runtime.h>
#include <hip/hip_bf16.h>
#include <math.h>

typedef __attribute__((ext_vector_type(8))) short bf16x8;
typedef __attribute__((ext_vector_type(4))) float f32x4;

#define SLAB 64   // max in-degree capacity per node (Poisson(16); P(>=64)~1e-13)

__device__ __forceinline__ unsigned short f2bf(float f) {
    union { float f; unsigned u; } v; v.f = f;
    unsigned r = v.u + 0x7FFFu + ((v.u >> 16) & 1u);   // RNE
    return (unsigned short)(r >> 16);
}
__device__ __forceinline__ float bflo(unsigned g) {
    union { unsigned u; float f; } v; v.u = g << 16; return v.f;
}
__device__ __forceinline__ float bfhi(unsigned g) {
    union { unsigned u; float f; } v; v.u = g & 0xFFFF0000u; return v.f;
}

// ---------------------------------------------------------------------------
// Weight prep: 6 [128][128] fp32 -> transposed bf16 Wt[col][k]
// ---------------------------------------------------------------------------
__global__ void prep_weights(const float* __restrict__ W_in,
                             const float* __restrict__ Wc,
                             const float* __restrict__ W_out,
                             unsigned short* __restrict__ Wt) {
    int idx = blockIdx.x * 256 + threadIdx.x;      // 6*16384 total
    int m = idx >> 14;
    int e = idx & 16383;
    if (m >= 6) return;
    const float* src = (m == 0) ? W_in : (m <= 4 ? Wc + (size_t)(m - 1) * 16384 : W_out);
    int k = e >> 7, c = e & 127;
    Wt[(size_t)m * 16384 + c * 128 + k] = f2bf(src[k * 128 + c]);
}

__global__ void prep_we1(const float* __restrict__ We1, unsigned short* __restrict__ Bt_e) {
    int idx = blockIdx.x * 256 + threadIdx.x;
    if (idx >= 96 * 32) return;
    int c = idx >> 5, k = idx & 31;
    Bt_e[idx] = f2bf(We1[k * 96 + c]);
}

// ---------------------------------------------------------------------------
// FUSED edge MLP + slab build. One wave = 16 edges, single K=32 MFMA pass.
// After the shfl_xor butterfly every lane holds its 16-group's sums, so
// lanes r<4 of each group own one edge each: sigmoid -> atomic slot -> store.
// ---------------------------------------------------------------------------
__launch_bounds__(256)
__global__ void edge_mlp_slab(const float* __restrict__ edge_attr,
                              const unsigned short* __restrict__ Bt_e,
                              const float* __restrict__ be1,
                              const float* __restrict__ We2,
                              const float* __restrict__ be2,
                              const int* __restrict__ ei,
                              int* __restrict__ cnt, int2* __restrict__ slab,
                              int E_, int nwaves) {
    const int lane = threadIdx.x & 63;
    const int r = lane & 15;
    const int kb = lane >> 4;
    const int wid0 = blockIdx.x * 4 + (threadIdx.x >> 6);

    bf16x8 bfrag[6];
    float be1v[6], we2v[6];
#pragma unroll
    for (int f = 0; f < 6; ++f) {
        int col = f * 16 + r;
        bfrag[f] = *(const bf16x8*)(Bt_e + col * 32 + kb * 8);
        be1v[f] = be1[col];
        we2v[f] = We2[col];
    }
    const float b2 = be2[0];

    const int ntiles = (E_ + 15) >> 4;
    for (int t = wid0; t < ntiles; t += nwaves) {
        const int e0 = t << 4;
        int arow = e0 + r; if (arow >= E_) arow = E_ - 1;
        const f32x4* ap = (const f32x4*)(edge_attr + (size_t)arow * 32 + kb * 8);
        f32x4 a0 = ap[0], a1 = ap[1];
        bf16x8 af;
        af[0] = (short)f2bf(a0[0]); af[1] = (short)f2bf(a0[1]);
        af[2] = (short)f2bf(a0[2]); af[3] = (short)f2bf(a0[3]);
        af[4] = (short)f2bf(a1[0]); af[5] = (short)f2bf(a1[1]);
        af[6] = (short)f2bf(a1[2]); af[7] = (short)f2bf(a1[3]);

        f32x4 zero = {0.f, 0.f, 0.f, 0.f};
        f32x4 acc[6];
#pragma unroll
        for (int f = 0; f < 6; ++f)
            acc[f] = __builtin_amdgcn_mfma_f32_16x16x32_bf16(af, bfrag[f], zero, 0, 0, 0);

        float p[4];
#pragma unroll
        for (int j = 0; j < 4; ++j) {
            float s = 0.f;
#pragma unroll
            for (int f = 0; f < 6; ++f)
                s = fmaf(fmaxf(acc[f][j] + be1v[f], 0.f), we2v[f], s);
            // butterfly: ALL lanes in each 16-group end with the group sum
            s += __shfl_xor(s, 1, 64);
            s += __shfl_xor(s, 2, 64);
            s += __shfl_xor(s, 4, 64);
            s += __shfl_xor(s, 8, 64);
            p[j] = s;
        }
        // lanes r=0..3 of group kb own edge e0 + kb*4 + r
        if (r < 4) {
            float pv = (r == 0) ? p[0] : (r == 1) ? p[1] : (r == 2) ? p[2] : p[3];
            int e = e0 + kb * 4 + r;
            if (e < E_) {
                float w = 1.f / (1.f + expf(-(pv + b2)));
                int src = ei[e];
                int dst = ei[E_ + e];
                int seq = atomicAdd(&cnt[dst], 1);
                if (seq < SLAB) {
                    int2 pp; pp.x = src; pp.y = __float_as_int(w);
                    slab[((size_t)dst << 6) + seq] = pp;
                }
            }
        }
    }
}

// deg = 1 (self loop) + sum slab ew ; dis = deg^-0.5   (no atomics)
__global__ void deg_dis(const int2* __restrict__ slab, const int* __restrict__ cnt,
                        float* __restrict__ dis, int n) {
    int v = blockIdx.x * 256 + threadIdx.x;
    if (v >= n) return;
    size_t base = (size_t)v << 6;
    int c = min(cnt[v], SLAB);
    float deg = 1.f;
    for (int i = 0; i < c; ++i) deg += __int_as_float(slab[base + i].y);
    dis[v] = 1.f / sqrtf(deg);
}

// in-place: slab.y = dis[v] * dis[src] * ew
__global__ void slab_norm(int2* __restrict__ slab, const int* __restrict__ cnt,
                          const float* __restrict__ dis, int n) {
    int v = blockIdx.x * 256 + threadIdx.x;
    if (v >= n) return;
    float dv = dis[v];
    size_t base = (size_t)v << 6;
    int c = min(cnt[v], SLAB);
    for (int i = 0; i < c; ++i) {
        int2 p = slab[base + i];
        slab[base + i].y = __float_as_int(dv * dis[p.x] * __int_as_float(p.y));
    }
}

// ---------------------------------------------------------------------------
// Node GEMM: C[M,128] = A[M,128] @ W[128,128] (+bias)(+relu)
// MODE: 0 plain, 1 bias+relu, 2 bias ; IT/OT: float or ushort(bf16)
// ---------------------------------------------------------------------------
template<int MODE, typename IT, typename OT>
__launch_bounds__(256)
__global__ void gemm_node(const IT* __restrict__ A, const unsigned short* __restrict__ Bt,
                          const float* __restrict__ bias, OT* __restrict__ C, int M) {
    const int lane = threadIdx.x & 63;
    const int wave = threadIdx.x >> 6;
    const int row0 = blockIdx.x * 64 + wave * 16;
    const int r = lane & 15;
    const int kb = lane >> 4;

    int arow = row0 + r;
    if (arow >= M) arow = M - 1;
    const IT* ap = A + (size_t)arow * 128 + kb * 8;

    f32x4 acc[8] = {};

#pragma unroll
    for (int kc = 0; kc < 4; ++kc) {
        bf16x8 af;
        if constexpr (sizeof(IT) == 2) {
            af = *(const bf16x8*)(ap + kc * 32);
        } else {
            f32x4 a0 = *(const f32x4*)(ap + kc * 32);
            f32x4 a1 = *(const f32x4*)(ap + kc * 32 + 4);
            af[0] = (short)f2bf(a0[0]); af[1] = (short)f2bf(a0[1]);
            af[2] = (short)f2bf(a0[2]); af[3] = (short)f2bf(a0[3]);
            af[4] = (short)f2bf(a1[0]); af[5] = (short)f2bf(a1[1]);
            af[6] = (short)f2bf(a1[2]); af[7] = (short)f2bf(a1[3]);
        }
#pragma unroll
        for (int f = 0; f < 8; ++f) {
            const int col = f * 16 + r;
            bf16x8 bfr = *(const bf16x8*)(Bt + col * 128 + kc * 32 + kb * 8);
            acc[f] = __builtin_amdgcn_mfma_f32_16x16x32_bf16(af, bfr, acc[f], 0, 0, 0);
        }
    }

    const int r4 = (lane >> 4) * 4;
#pragma unroll
    for (int f = 0; f < 8; ++f) {
        int col = f * 16 + (lane & 15);
        float bv = (MODE > 0) ? bias[col] : 0.f;
#pragma unroll
        for (int j = 0; j < 4; ++j) {
            int row = row0 + r4 + j;
            if (row < M) {
                float v = acc[f][j] + bv;
                if (MODE == 1) v = fmaxf(v, 0.f);
                if constexpr (sizeof(OT) == 2) C[(size_t)row * 128 + col] = (OT)f2bf(v);
                else                           C[(size_t)row * 128 + col] = v;
            }
        }
    }
}

// ---------------------------------------------------------------------------
// Aggregation: h = relu( hW[n]*dis^2 + sum_in hW[src]*norm + bc + h )
// Uniform masked 16-batches: every wave keeps ~16 row-gathers in flight
// (dup-clamped indices for the tail, weight 0). One wave per node.
// ---------------------------------------------------------------------------
__launch_bounds__(256)
__global__ void agg_layer(const unsigned int* __restrict__ hWb, unsigned int* __restrict__ hb,
                          const int2* __restrict__ slab, const int* __restrict__ cnt,
                          const float* __restrict__ dis, const float* __restrict__ bc_i, int n) {
    int node = blockIdx.x * 4 + (threadIdx.x >> 6);
    if (node >= n) return;
    int lane = threadIdx.x & 63;

    const int c = min(cnt[node], SLAB);
    float d = dis[node];
    float sw = d * d;
    unsigned gs = hWb[(size_t)node * 64 + lane];
    float2 acc = make_float2(bflo(gs) * sw, bfhi(gs) * sw);

    const size_t base = (size_t)node << 6;
    for (int s = 0; s < c; s += 16) {
        const int rem = c - s;           // wave-uniform
        int2 p[16]; unsigned g[16];
#pragma unroll
        for (int i = 0; i < 16; ++i) p[i] = slab[base + (i < rem ? s + i : s)];
#pragma unroll
        for (int i = 0; i < 16; ++i) g[i] = hWb[(size_t)p[i].x * 64 + lane];
#pragma unroll
        for (int i = 0; i < 16; ++i) {
            float w = (i < rem) ? __int_as_float(p[i].y) : 0.f;
            acc.x = fmaf(bflo(g[i]), w, acc.x);
            acc.y = fmaf(bfhi(g[i]), w, acc.y);
        }
    }

    unsigned hr = hb[(size_t)node * 64 + lane];
    float2 b = ((const float2*)bc_i)[lane];
    float ox = fmaxf(acc.x + bflo(hr) + b.x, 0.f);
    float oy = fmaxf(acc.y + bfhi(hr) + b.y, 0.f);
    hb[(size_t)node * 64 + lane] = (unsigned)f2bf(ox) | ((unsigned)f2bf(oy) << 16);
}

// ---------------------------------------------------------------------------
extern "C" void kernel_launch(void* const* d_in, const int* in_sizes, int n_in,
                              void* d_out, int out_size, void* d_ws, size_t ws_size,
                              hipStream_t stream) {
    const float* x     = (const float*)d_in[0];
    const int*   ei    = (const int*)d_in[1];
    const float* eattr = (const float*)d_in[2];
    const float* W_in  = (const float*)d_in[3];
    const float* b_in  = (const float*)d_in[4];
    const float* We1   = (const float*)d_in[5];
    const float* be1   = (const float*)d_in[6];
    const float* We2   = (const float*)d_in[7];
    const float* be2   = (const float*)d_in[8];
    const float* Wc    = (const float*)d_in[9];
    const float* bc    = (const float*)d_in[10];
    const float* W_out = (const float*)d_in[11];
    const float* b_out = (const float*)d_in[12];
    float* out = (float*)d_out;

    const int N_ = in_sizes[0] / 128;
    const int E_ = in_sizes[1] / 2;

    size_t ofsb = 0;
    char* wsb = (char*)d_ws;
    auto carve = [&](size_t nbytes) -> char* {
        char* p = wsb + ofsb;
        ofsb += (nbytes + 511) & ~(size_t)511;
        return p;
    };
    int*   cnt  = (int*)carve((size_t)N_ * 4);
    float* dis  = (float*)carve((size_t)N_ * 4);
    int2*  slab = (int2*)carve((size_t)N_ * SLAB * 8);
    unsigned int* hb  = (unsigned int*)carve((size_t)N_ * 256);   // h bf16
    unsigned int* hWb = (unsigned int*)carve((size_t)N_ * 256);   // hW bf16
    unsigned short* Wt   = (unsigned short*)carve(6 * 16384 * 2);
    unsigned short* Bt_e = (unsigned short*)carve(96 * 32 * 2);

    const int nb = (N_ + 255) / 256;

    // 1. weight prep
    prep_weights<<<384, 256, 0, stream>>>(W_in, Wc, W_out, Wt);
    prep_we1<<<12, 256, 0, stream>>>(We1, Bt_e);

    // 2+3. fused edge MLP + slab build (single atomic pass), then deg/dis/norm
    hipMemsetAsync(cnt, 0, (size_t)N_ * 4, stream);
    const int mlp_blocks = 4096;
    edge_mlp_slab<<<mlp_blocks, 256, 0, stream>>>(eattr, Bt_e, be1, We2, be2, ei,
                                                  cnt, slab, E_, mlp_blocks * 4);
    deg_dis<<<nb, 256, 0, stream>>>(slab, cnt, dis, N_);
    slab_norm<<<nb, 256, 0, stream>>>(slab, cnt, dis, N_);

    // 4. input projection: h = relu(x @ W_in + b_in)  (h stored bf16)
    const int gb = (N_ + 63) / 64;
    gemm_node<1, float, unsigned short><<<gb, 256, 0, stream>>>(
        x, Wt, b_in, (unsigned short*)hb, N_);

    // 5. 4 GCN layers
    const int ab = (N_ + 3) / 4;
    for (int i = 0; i < 4; ++i) {
        gemm_node<0, unsigned short, unsigned short><<<gb, 256, 0, stream>>>(
            (const unsigned short*)hb, Wt + (size_t)(1 + i) * 16384, nullptr,
            (unsigned short*)hWb, N_);
        agg_layer<<<ab, 256, 0, stream>>>(hWb, hb, slab, cnt, dis,
                                          bc + (size_t)i * 128, N_);
    }

    // 6. output projection
    gemm_node<2, unsigned short, float><<<gb, 256, 0, stream>>>(
        (const unsigned short*)hb, Wt + (size_t)5 * 16384, b_out, out, N_);
}